// Round 8
// baseline (114.918 us; speedup 1.0000x reference)
//
#include <hip/hip_runtime.h>
#include <hip/hip_bf16.h>

// CustomAttention: proj = tanh(H @ W^T + b); scores = proj @ c; attn = softmax_L(scores);
// out0 = sum_l H * attn ; out1 = attn.   B=64, L=512, D=768.  M = B*L = 32768.
// Round 8: one-pass GEMM. BM=128, BN=768 (FULL N per block -> A read exactly once,
// no score partials), BK=32, 8 waves (2Mx4N, acc 4x12), 256 blocks = 1 round.
// LDS: packed-pair 128-B rows (two logical rows per LDS row) so the proven
// (row&7)-XOR 16B-unit swizzle applies at BK=32; dbuf 2x(8+48) KB, 1 barrier/step.

using half8 = __attribute__((ext_vector_type(8))) _Float16;   // MFMA A/B frag (4 VGPRs)
using f32x4 = __attribute__((ext_vector_type(4))) float;      // MFMA C/D frag

#define AS1 __attribute__((address_space(1)))
#define AS3 __attribute__((address_space(3)))

__device__ __forceinline__ void gload_lds16(const void* g, void* l) {
  __builtin_amdgcn_global_load_lds((const AS1 void*)g, (AS3 void*)l, 16, 0, 0);
}

__device__ __forceinline__ unsigned short f2h(float x) {
  _Float16 h = (_Float16)x;                       // v_cvt_f16_f32, RNE
  return __builtin_bit_cast(unsigned short, h);
}

// tanh(x) = 1 - 2/(exp(2x)+1).
__device__ __forceinline__ float tanh_fast(float x) {
  return 1.0f - __fdividef(2.0f, 1.0f + __expf(2.0f * x));
}

// ---------------- conversion kernels ----------------

__global__ void convert_h(const float4* __restrict__ H4, ushort4* __restrict__ Ah) {
  int i = blockIdx.x * 256 + threadIdx.x;   // 6291456 quads
  float4 x = H4[i];
  ushort4 o;
  o.x = f2h(x.x); o.y = f2h(x.y); o.z = f2h(x.z); o.w = f2h(x.w);
  Ah[i] = o;
}

__global__ void convert_w(const float4* __restrict__ W4, ushort4* __restrict__ Wt) {
  int i = blockIdx.x * 256 + threadIdx.x;   // 147456 quads
  float4 x = W4[i];
  ushort4 o;
  o.x = f2h(x.x); o.y = f2h(x.y); o.z = f2h(x.z); o.w = f2h(x.w);
  Wt[i] = o;
}

// ---------------- one-pass GEMM + tanh/context epilogue ----------------
// LDS layout (per slot), packed-pair 128-B rows:
//   A: 64 ldsrows x 128 B. Logical (Arow in [0,128), k in [0,32)):
//      half=Arow>>6, lr=Arow&63, u=k>>3, u'=half*4+u, slot=u'^(lr&7),
//      byte = lr*128 + slot*16 + (k&7)*2.
//   B: 384 ldsrows x 128 B. Logical (Nrow in [0,768), k): half=Nrow>=384,
//      lr=Nrow-384*half, same slot formula.
// Staging writes LDS linearly (gload_lds); the global SOURCE address is the
// layout inverse (both-sides rule).  Reads use the same slot formula ->
// 16 lanes/frag hit 8 distinct 16B slots (2 lanes each) = conflict-free
// (same math as the r1-r4 measured-0-conflict layout).
__global__ __launch_bounds__(512) void gemm_scores(
    const ushort* __restrict__ Ah, const ushort* __restrict__ Wt,
    const float* __restrict__ bias, const float* __restrict__ cvec,
    float* __restrict__ part) {
  __shared__ ushort ldsA[2][4096];     // 2 x 8 KB
  __shared__ ushort ldsB[2][24576];    // 2 x 48 KB
  __shared__ float scpart[4][128];     // 2 KB   (total 116736 B)

  const int tid = threadIdx.x;
  const int lane = tid & 63;
  const int wid = tid >> 6;            // 0..7
  const int wr = wid >> 2;             // 0..1  (M half: rows wr*64..)
  const int wc = wid & 3;              // 0..3  (N slice: cols wc*192..)
  const int m = lane & 15, q = lane >> 4;
  const int mtile = blockIdx.x;        // 0..255

  const char* const Abase = (const char*)Ah + (size_t)(mtile * 128) * 1536;
  const char* const Bbase = (const char*)Wt;

  // --- staging source precompute (inverse of the LDS layout) ---
  // A: thread t writes LDS bytes [t*16,+16): lr=t>>3, slot=t&7, u'=slot^(lr&7)
  const int alr = tid >> 3;
  const int au = (tid & 7) ^ (alr & 7);
  const size_t asrc = (size_t)(alr + 64 * (au >> 2)) * 1536 + (au & 3) * 16;
  // B: thread t, chunk c writes bytes [c*8192 + t*16,+16): lr=c*64+(t>>3),
  // slot=t&7, lr&7=(t>>3)&7 (c*64 = 0 mod 8) -> u' same for all c.
  const int bu = (tid & 7) ^ ((tid >> 3) & 7);
  const size_t bsrc0 = (size_t)((tid >> 3) + 384 * (bu >> 2)) * 1536 + (bu & 3) * 16;
  const int wavebase = wid << 10;

  f32x4 acc[4][12];
  #pragma unroll
  for (int i = 0; i < 4; ++i)
    #pragma unroll
    for (int j = 0; j < 12; ++j)
      acc[i][j] = (f32x4){0.f, 0.f, 0.f, 0.f};

  auto stage = [&](int kt, int s) {
    gload_lds16(Abase + asrc + kt * 64, (char*)ldsA[s] + wavebase);
    #pragma unroll
    for (int c = 0; c < 6; ++c)
      gload_lds16(Bbase + bsrc0 + c * 98304 + kt * 64,
                  (char*)ldsB[s] + c * 8192 + wavebase);
  };

  // read-side swizzled offsets (bytes within a 128-B row)
  const int aslot = ((wr * 4 + q) ^ (m & 7)) * 16;          // A: half = wr
  const int bslot = (((wc >> 1) * 4 + q) ^ (m & 7)) * 16;   // B: half = wc>>1
  const int blr0 = (wc & 1) * 192;                          // B ldsrow base

  auto compute = [&](int s) {
    const char* Ab = (const char*)ldsA[s];
    const char* Bb = (const char*)ldsB[s];
    half8 areg[4];
    #pragma unroll
    for (int mi = 0; mi < 4; ++mi)
      areg[mi] = *(const half8*)(Ab + (mi * 16 + m) * 128 + aslot);
    #pragma unroll
    for (int ni = 0; ni < 12; ++ni) {
      half8 breg = *(const half8*)(Bb + (blr0 + ni * 16 + m) * 128 + bslot);
      #pragma unroll
      for (int mi = 0; mi < 4; ++mi)
        acc[mi][ni] = __builtin_amdgcn_mfma_f32_16x16x32_f16(
            areg[mi], breg, acc[mi][ni], 0, 0, 0);
    }
  };

  // --- dbuf loop: stage(t+1) | compute(t) | sync  (r4-proven single barrier) ---
  stage(0, 0);
  __syncthreads();
  #pragma unroll 2
  for (int t = 0; t < 24; ++t) {
    if (t + 1 < 24) stage(t + 1, (t + 1) & 1);
    compute(t & 1);
    __syncthreads();
  }

  // epilogue: score = sum_e tanh(acc + b[e]) * c[e]
  float bb[12], cc[12];
  #pragma unroll
  for (int ni = 0; ni < 12; ++ni) {
    int e = wc * 192 + ni * 16 + m;
    bb[ni] = bias[e];
    cc[ni] = cvec[e];
  }
  #pragma unroll
  for (int mi = 0; mi < 4; ++mi) {
    #pragma unroll
    for (int j = 0; j < 4; ++j) {
      float s = 0.f;
      #pragma unroll
      for (int ni = 0; ni < 12; ++ni)
        s += tanh_fast(acc[mi][ni][j] + bb[ni]) * cc[ni];
      s += __shfl_xor(s, 1);
      s += __shfl_xor(s, 2);
      s += __shfl_xor(s, 4);
      s += __shfl_xor(s, 8);
      if (m == 0) scpart[wc][wr * 64 + mi * 16 + q * 4 + j] = s;
    }
  }
  __syncthreads();
  if (tid < 128)
    part[mtile * 128 + tid] =
        scpart[0][tid] + scpart[1][tid] + scpart[2][tid] + scpart[3][tid];
}

// ---------------- fused softmax + weighted sum ----------------
__global__ void wsum_fused(const ushort* __restrict__ Ah, const float* __restrict__ prt,
                           float* __restrict__ out) {
  int b = blockIdx.x, dc = blockIdx.y;   // grid (64,3), 128 threads
  int t = threadIdx.x;
  __shared__ float w[512];
  __shared__ float redm[2], reds[2];

  float s[4];
  #pragma unroll
  for (int i = 0; i < 4; ++i) s[i] = prt[b * 512 + t + i * 128];
  float mx = fmaxf(fmaxf(s[0], s[1]), fmaxf(s[2], s[3]));
  #pragma unroll
  for (int o = 32; o >= 1; o >>= 1) mx = fmaxf(mx, __shfl_xor(mx, o));
  if ((t & 63) == 0) redm[t >> 6] = mx;
  __syncthreads();
  mx = fmaxf(redm[0], redm[1]);

  float e[4], sm = 0.f;
  #pragma unroll
  for (int i = 0; i < 4; ++i) { e[i] = __expf(s[i] - mx); sm += e[i]; }
  #pragma unroll
  for (int o = 32; o >= 1; o >>= 1) sm += __shfl_xor(sm, o);
  if ((t & 63) == 0) reds[t >> 6] = sm;
  __syncthreads();
  float inv = 1.0f / (reds[0] + reds[1]);
  #pragma unroll
  for (int i = 0; i < 4; ++i) w[t + i * 128] = e[i] * inv;
  __syncthreads();

  int d0 = dc * 256 + t * 2;
  const ushort* hp = Ah + (size_t)b * 512 * 768 + d0;
  float a0 = 0.f, a1 = 0.f;
  #pragma unroll 8
  for (int l = 0; l < 512; ++l) {
    unsigned u = *(const unsigned*)(hp + (size_t)l * 768);
    float wl = w[l];
    a0 += wl * (float)__builtin_bit_cast(_Float16, (unsigned short)(u & 0xffff));
    a1 += wl * (float)__builtin_bit_cast(_Float16, (unsigned short)(u >> 16));
  }
  out[b * 768 + d0] = a0;
  out[b * 768 + d0 + 1] = a1;

  if (dc == 0) {
    #pragma unroll
    for (int i = 0; i < 4; ++i)
      out[49152 + b * 512 + t + i * 128] = w[t + i * 128];
  }
}

// ---------------- launch ----------------
extern "C" void kernel_launch(void* const* d_in, const int* in_sizes, int n_in,
                              void* d_out, int out_size, void* d_ws, size_t ws_size,
                              hipStream_t stream) {
  const float* H    = (const float*)d_in[0];
  const float* W    = (const float*)d_in[1];
  const float* bias = (const float*)d_in[2];
  const float* cvec = (const float*)d_in[3];
  float* out = (float*)d_out;

  char* ws = (char*)d_ws;
  ushort* Ah = (ushort*)(ws + 0);              // 50,331,648 B
  ushort* Wt = (ushort*)(ws + 50331648);       //  1,179,648 B
  float*  prt = (float*)(ws + 51511296);       //    131,072 B ([32768])

  hipLaunchKernelGGL(convert_h, dim3(24576), dim3(256), 0, stream,
                     (const float4*)H, (ushort4*)Ah);
  hipLaunchKernelGGL(convert_w, dim3(576), dim3(256), 0, stream,
                     (const float4*)W, (ushort4*)Wt);
  hipLaunchKernelGGL(gemm_scores, dim3(256), dim3(512), 0, stream,
                     Ah, Wt, bias, cvec, prt);
  hipLaunchKernelGGL(wsum_fused, dim3(64, 3), dim3(128), 0, stream,
                     Ah, prt, out);
}

// Round 9
// 103.110 us; speedup vs baseline: 1.1145x; 1.1145x over previous
//
#include <hip/hip_runtime.h>
#include <hip/hip_bf16.h>

// CustomAttention: proj = tanh(H @ W^T + b); scores = proj @ c; attn = softmax_L(scores);
// out0 = sum_l H * attn ; out1 = attn.   B=64, L=512, D=768.  M = B*L = 32768.
// Round 9: staged-traffic-optimal tiling. Staged bytes = M*N*K*2*(1/BM+1/BN):
// r4's 128x128 -> 604 MB @ ~7 TB/s = 82 us.  BM=256, BN=384 -> 251 MB.
// 256 blocks = exactly 1 round on 256 CUs; 8 waves (4Mx2N), acc 4x12 (r8-proven
// shape); BK=32, dbuf 2x(16+24) KB with packed-pair conflict-free LDS rows;
// single barrier per step (r4-proven loop).

using half8 = __attribute__((ext_vector_type(8))) _Float16;   // MFMA A/B frag (4 VGPRs)
using f32x4 = __attribute__((ext_vector_type(4))) float;      // MFMA C/D frag

#define AS1 __attribute__((address_space(1)))
#define AS3 __attribute__((address_space(3)))

__device__ __forceinline__ void gload_lds16(const void* g, void* l) {
  __builtin_amdgcn_global_load_lds((const AS1 void*)g, (AS3 void*)l, 16, 0, 0);
}

__device__ __forceinline__ unsigned short f2h(float x) {
  _Float16 h = (_Float16)x;                       // v_cvt_f16_f32, RNE
  return __builtin_bit_cast(unsigned short, h);
}

// tanh(x) = 1 - 2/(exp(2x)+1).
__device__ __forceinline__ float tanh_fast(float x) {
  return 1.0f - __fdividef(2.0f, 1.0f + __expf(2.0f * x));
}

// ---------------- conversion kernels ----------------

__global__ void convert_h(const float4* __restrict__ H4, ushort4* __restrict__ Ah) {
  int i = blockIdx.x * 256 + threadIdx.x;   // 6291456 quads
  float4 x = H4[i];
  ushort4 o;
  o.x = f2h(x.x); o.y = f2h(x.y); o.z = f2h(x.z); o.w = f2h(x.w);
  Ah[i] = o;
}

__global__ void convert_w(const float4* __restrict__ W4, ushort4* __restrict__ Wt) {
  int i = blockIdx.x * 256 + threadIdx.x;   // 147456 quads
  float4 x = W4[i];
  ushort4 o;
  o.x = f2h(x.x); o.y = f2h(x.y); o.z = f2h(x.z); o.w = f2h(x.w);
  Wt[i] = o;
}

// ---------------- GEMM (BM=256, BN=384, BK=32) + tanh/context epilogue --------
// LDS packed-pair 128-B rows (r8's measured-0-conflict layout):
//   A: 128 ldsrows x 128 B.  Logical (Arow in [0,256), k in [0,32)):
//      half=Arow>>7, lr=Arow&127, u'=half*4+(k>>3), slot=u'^(lr&7),
//      byte = lr*128 + slot*16 + (k&7)*2.
//   B: 192 ldsrows x 128 B.  Logical (Nrow in [0,768-block-local 384), k):
//      half=Nrow/192, lr=Nrow%192, same slot formula.
// Staging writes LDS linearly (gload_lds: wave-uniform base + lane*16); the
// global SOURCE address is the layout inverse (both-sides rule).
// Grid decode: xcd=bid&7, sid=bid>>3; mtile=xcd*16+(sid>>1), ntile=sid&1 ->
// the two same-mtile blocks sit on one XCD (A's 2nd read L2/L3-local).
__global__ __launch_bounds__(512) void gemm_scores(
    const ushort* __restrict__ Ah, const ushort* __restrict__ Wt,
    const float* __restrict__ bias, const float* __restrict__ cvec,
    float* __restrict__ part) {
  __shared__ ushort ldsAll[40960];     // 81,920 B total
  ushort* const ldsA0 = ldsAll;            // 16 KB (slot 0 A)
  ushort* const ldsA1 = ldsAll + 8192;     // 16 KB (slot 1 A)
  ushort* const ldsB0 = ldsAll + 16384;    // 24 KB (slot 0 B)
  ushort* const ldsB1 = ldsAll + 28672;    // 24 KB (slot 1 B)
  float* const scpart = (float*)ldsAll;    // [2][256] aliases A after final barrier

  const int tid = threadIdx.x;
  const int lane = tid & 63;
  const int wid = tid >> 6;            // 0..7
  const int wr = wid >> 1;             // 0..3  (M quarter: rows wr*64..)
  const int wc = wid & 1;              // 0..1  (N half: cols wc*192..)
  const int m = lane & 15, q = lane >> 4;

  const int bid = blockIdx.x;          // 0..255
  const int xcd = bid & 7;
  const int sid = bid >> 3;            // 0..31
  const int mtile = xcd * 16 + (sid >> 1);   // 0..127
  const int ntile = sid & 1;                 // 0..1

  const char* const Abase = (const char*)Ah + (size_t)(mtile * 256) * 1536;
  const char* const Bbase = (const char*)Wt + (size_t)(ntile * 384) * 1536;

  // --- staging source precompute (inverse of the LDS layout) ---
  // thread t, chunk c: LDS byte = c*8192 + t*16 -> lr = c*64 + (t>>3),
  // slot = t&7, u' = slot ^ ((t>>3)&7)  (c*64 == 0 mod 8 -> c-independent)
  const int up = (tid & 7) ^ ((tid >> 3) & 7);
  const int tr3 = tid >> 3;
  // A: row = (u'>>2)*128 + lr; col byte = (u'&3)*16
  const size_t asrc = (size_t)((up >> 2) * 128 + tr3) * 1536 + (up & 3) * 16;
  // B: row = (u'>>2)*192 + lr
  const size_t bsrc = (size_t)((up >> 2) * 192 + tr3) * 1536 + (up & 3) * 16;
  const int wavebase = wid << 10;

  f32x4 acc[4][12];
  #pragma unroll
  for (int i = 0; i < 4; ++i)
    #pragma unroll
    for (int j = 0; j < 12; ++j)
      acc[i][j] = (f32x4){0.f, 0.f, 0.f, 0.f};

  auto stage = [&](int kt, ushort* dA, ushort* dB) {
    #pragma unroll
    for (int c = 0; c < 2; ++c)
      gload_lds16(Abase + asrc + (size_t)c * 64 * 1536 + kt * 64,
                  (char*)dA + c * 8192 + wavebase);
    #pragma unroll
    for (int c = 0; c < 3; ++c)
      gload_lds16(Bbase + bsrc + (size_t)c * 64 * 1536 + kt * 64,
                  (char*)dB + c * 8192 + wavebase);
  };

  // read-side swizzled byte offsets within a 128-B ldsrow
  const int aslot = (((wr >> 1) * 4 + q) ^ (m & 7)) * 16;  // A: half = wr>>1
  const int alr0 = (wr & 1) * 64;                          // A ldsrow base
  const int bslot = ((wc * 4 + q) ^ (m & 7)) * 16;         // B: half = wc
  // B ldsrow = ni*16 + m

  auto compute = [&](const ushort* As, const ushort* Bs) {
    const char* Ab = (const char*)As;
    const char* Bb = (const char*)Bs;
    half8 areg[4];
    #pragma unroll
    for (int mi = 0; mi < 4; ++mi)
      areg[mi] = *(const half8*)(Ab + (alr0 + mi * 16 + m) * 128 + aslot);
    #pragma unroll
    for (int ni = 0; ni < 12; ++ni) {
      half8 breg = *(const half8*)(Bb + (ni * 16 + m) * 128 + bslot);
      #pragma unroll
      for (int mi = 0; mi < 4; ++mi)
        acc[mi][ni] = __builtin_amdgcn_mfma_f32_16x16x32_f16(
            areg[mi], breg, acc[mi][ni], 0, 0, 0);
    }
  };

  // --- dbuf loop: stage(t+1) | compute(t) | sync ---
  stage(0, ldsA0, ldsB0);
  __syncthreads();
  #pragma unroll 2
  for (int t = 0; t < 24; ++t) {
    ushort* dA = (t & 1) ? ldsA0 : ldsA1;
    ushort* dB = (t & 1) ? ldsB0 : ldsB1;
    const ushort* sA = (t & 1) ? ldsA1 : ldsA0;
    const ushort* sB = (t & 1) ? ldsB1 : ldsB0;
    if (t + 1 < 24) stage(t + 1, dA, dB);
    compute(sA, sB);
    __syncthreads();
  }

  // epilogue: score = sum_e tanh(acc + b[e]) * c[e]   (scpart aliases ldsA)
  float bb[12], cc[12];
  #pragma unroll
  for (int ni = 0; ni < 12; ++ni) {
    int e = ntile * 384 + wc * 192 + ni * 16 + m;
    bb[ni] = bias[e];
    cc[ni] = cvec[e];
  }
  #pragma unroll
  for (int mi = 0; mi < 4; ++mi) {
    #pragma unroll
    for (int j = 0; j < 4; ++j) {
      float s = 0.f;
      #pragma unroll
      for (int ni = 0; ni < 12; ++ni)
        s += tanh_fast(acc[mi][ni][j] + bb[ni]) * cc[ni];
      s += __shfl_xor(s, 1);
      s += __shfl_xor(s, 2);
      s += __shfl_xor(s, 4);
      s += __shfl_xor(s, 8);
      if (m == 0) scpart[wc * 256 + wr * 64 + mi * 16 + q * 4 + j] = s;
    }
  }
  __syncthreads();
  if (tid < 256)
    part[ntile * 32768 + mtile * 256 + tid] = scpart[tid] + scpart[256 + tid];
}

// ---------------- fused softmax + weighted sum ----------------
__global__ void wsum_fused(const ushort* __restrict__ Ah, const float* __restrict__ prt,
                           float* __restrict__ out) {
  int b = blockIdx.x, dc = blockIdx.y;   // grid (64,3), 128 threads
  int t = threadIdx.x;
  __shared__ float w[512];
  __shared__ float redm[2], reds[2];

  float s[4];
  #pragma unroll
  for (int i = 0; i < 4; ++i) {
    int r = b * 512 + t + i * 128;
    s[i] = prt[r] + prt[32768 + r];
  }
  float mx = fmaxf(fmaxf(s[0], s[1]), fmaxf(s[2], s[3]));
  #pragma unroll
  for (int o = 32; o >= 1; o >>= 1) mx = fmaxf(mx, __shfl_xor(mx, o));
  if ((t & 63) == 0) redm[t >> 6] = mx;
  __syncthreads();
  mx = fmaxf(redm[0], redm[1]);

  float e[4], sm = 0.f;
  #pragma unroll
  for (int i = 0; i < 4; ++i) { e[i] = __expf(s[i] - mx); sm += e[i]; }
  #pragma unroll
  for (int o = 32; o >= 1; o >>= 1) sm += __shfl_xor(sm, o);
  if ((t & 63) == 0) reds[t >> 6] = sm;
  __syncthreads();
  float inv = 1.0f / (reds[0] + reds[1]);
  #pragma unroll
  for (int i = 0; i < 4; ++i) w[t + i * 128] = e[i] * inv;
  __syncthreads();

  int d0 = dc * 256 + t * 2;
  const ushort* hp = Ah + (size_t)b * 512 * 768 + d0;
  float a0 = 0.f, a1 = 0.f;
  #pragma unroll 8
  for (int l = 0; l < 512; ++l) {
    unsigned u = *(const unsigned*)(hp + (size_t)l * 768);
    float wl = w[l];
    a0 += wl * (float)__builtin_bit_cast(_Float16, (unsigned short)(u & 0xffff));
    a1 += wl * (float)__builtin_bit_cast(_Float16, (unsigned short)(u >> 16));
  }
  out[b * 768 + d0] = a0;
  out[b * 768 + d0 + 1] = a1;

  if (dc == 0) {
    #pragma unroll
    for (int i = 0; i < 4; ++i)
      out[49152 + b * 512 + t + i * 128] = w[t + i * 128];
  }
}

// ---------------- launch ----------------
extern "C" void kernel_launch(void* const* d_in, const int* in_sizes, int n_in,
                              void* d_out, int out_size, void* d_ws, size_t ws_size,
                              hipStream_t stream) {
  const float* H    = (const float*)d_in[0];
  const float* W    = (const float*)d_in[1];
  const float* bias = (const float*)d_in[2];
  const float* cvec = (const float*)d_in[3];
  float* out = (float*)d_out;

  char* ws = (char*)d_ws;
  ushort* Ah = (ushort*)(ws + 0);              // 50,331,648 B
  ushort* Wt = (ushort*)(ws + 50331648);       //  1,179,648 B
  float*  prt = (float*)(ws + 51511296);       //    262,144 B ([2][32768])

  hipLaunchKernelGGL(convert_h, dim3(24576), dim3(256), 0, stream,
                     (const float4*)H, (ushort4*)Ah);
  hipLaunchKernelGGL(convert_w, dim3(576), dim3(256), 0, stream,
                     (const float4*)W, (ushort4*)Wt);
  hipLaunchKernelGGL(gemm_scores, dim3(256), dim3(512), 0, stream,
                     Ah, Wt, bias, cvec, prt);
  hipLaunchKernelGGL(wsum_fused, dim3(64, 3), dim3(128), 0, stream,
                     Ah, prt, out);
}